// Round 4
// baseline (337.109 us; speedup 1.0000x reference)
//
#include <hip/hip_runtime.h>
#include <hip/hip_bf16.h>
#include <cstdint>

// Problem constants (match reference)
#define B_ 256
#define N_ 131072
#define D_ 256
#define INV_TEMP 20.0f   // 1/0.05
#define EPS_SM 1e-6f
#define EPS_LOG 1e-6f

// GEMM tiling: 512 blocks (2/CU), each owns 256 cf rows. Chunk = 64 rows x 64 K.
#define TPB 512            // 8 waves; wave w owns A rows w*32..w*32+31
#define BROWS 256          // cf rows per block
#define BN 64              // cf rows per chunk
#define BK 64              // K elems per chunk
#define NCHUNK 16          // (BROWS/BN=4 N-groups) * (D_/BK=4 K-chunks)
#define LDB 72             // LDS row stride (elems): 64+8 pad, 16B-aligned rows (144B)
#define BUFE (BN * LDB)    // 4608 ushorts = 9.2KB per B buffer (dbuf fits in A-phase 36.8KB)
#define NSLOT 32
#define NBLK (N_ / BROWS)  // 512 blocks -> 2 per CU

typedef __bf16 bf16_t;
typedef bf16_t bf16x8 __attribute__((ext_vector_type(8)));
typedef float f32x4 __attribute__((ext_vector_type(4)));

struct alignas(16) U8 { ushort u[8]; };

// Native f32->bf16 (v_cvt_pk_bf16_f32, RNE) — same rounding as the old bit-twiddle.
__device__ inline ushort f2bf(float f) {
  return __builtin_bit_cast(ushort, (__bf16)f);
}

__device__ inline void cvt_store8(ushort* dst, const float4 a, const float4 b) {
  U8 w;
  w.u[0] = f2bf(a.x); w.u[1] = f2bf(a.y); w.u[2] = f2bf(a.z); w.u[3] = f2bf(a.w);
  w.u[4] = f2bf(b.x); w.u[5] = f2bf(b.y); w.u[6] = f2bf(b.z); w.u[7] = f2bf(b.w);
  *(uint4*)dst = __builtin_bit_cast(uint4, w);
}

// Barrier that orders LDS only — does NOT drain vmcnt, so in-flight global
// prefetch (register-destined, per-thread-consumed) survives the barrier.
// This is the T3/T4 "never vmcnt(0) in the main loop" fix for __syncthreads'
// mandatory vmcnt(0) drain.
__device__ inline void bar_ds() {
  asm volatile("s_waitcnt lgkmcnt(0)" ::: "memory");
  __builtin_amdgcn_s_barrier();
}

// VGPR budget: areg 64 + acc 32 + ldbuf 16 + rs 8 + addressing ~= 125.
// launch_bounds(512,4) caps at 128 so 2 blocks/CU co-reside.
__global__ __launch_bounds__(TPB, 4)
void gemm_rowsum_fused(const float* __restrict__ inp, const float* __restrict__ cf,
                       const int* __restrict__ idx, const int* __restrict__ lab,
                       float* __restrict__ rowsum, unsigned* __restrict__ counter,
                       float* __restrict__ out) {
  // 36.8KB: A-stage phase uses [256][LDB]; steady state uses first 2*BUFE as B dbuf.
  __shared__ ushort smem[B_ * LDB];
  __shared__ unsigned done;
  const int tid  = threadIdx.x;
  const int wave = tid >> 6;
  const int lane = tid & 63;
  const int m15  = lane & 15;
  const int q    = lane >> 4;

  const size_t nbase = (size_t)blockIdx.x * BROWS;
  // chunk staging: 64 rows x 64 cols fp32 = 8 floats/thread; 8 threads/row.
  const int brow = tid >> 3, bcg = tid & 7;
#define LDADDR(c) (cf + (nbase + (size_t)((c) >> 2) * BN + brow) * D_ + ((c) & 3) * BK + bcg * 8)

  // ---- Start the HBM-critical cf stream first (chunks 0,1 -> regs; 32B/thread each).
  float4 ldbuf[2][2];
  ldbuf[0][0] = *(const float4*)(LDADDR(0));
  ldbuf[0][1] = *(const float4*)(LDADDR(0) + 4);
  ldbuf[1][0] = *(const float4*)(LDADDR(1));
  ldbuf[1][1] = *(const float4*)(LDADDR(1) + 4);

  // ---- A phase: coalesced global -> LDS -> MFMA fragments (raw barriers: the
  // cf prefetch above stays in flight; __syncthreads would drain it).
  // areg[kc*2+ks][mb]: rows wave*32+mb*16+(lane&15), k = (kc*2+ks)*32 + q*8..+7
  bf16x8 areg[8][2];
#pragma unroll
  for (int kc = 0; kc < 4; ++kc) {
    const int row = tid >> 1, half = tid & 1;
    const float* src = inp + row * D_ + kc * BK + half * 32;
#pragma unroll
    for (int j = 0; j < 4; ++j) {
      const float4 v0 = *(const float4*)(src + j * 8);
      const float4 v1 = *(const float4*)(src + j * 8 + 4);
      cvt_store8(&smem[row * LDB + half * 32 + j * 8], v0, v1);
    }
    bar_ds();  // writes visible
#pragma unroll
    for (int mb = 0; mb < 2; ++mb)
#pragma unroll
      for (int ks = 0; ks < 2; ++ks)
        areg[kc * 2 + ks][mb] = __builtin_bit_cast(
            bf16x8, *(const uint4*)(&smem[(wave * 32 + mb * 16 + m15) * LDB + ks * 32 + q * 8]));
    bar_ds();  // frag reads drained before next kc overwrites
  }

  f32x4 acc[2][4];
  float rs[2][4];
#pragma unroll
  for (int mb = 0; mb < 2; ++mb) {
#pragma unroll
    for (int nb = 0; nb < 4; ++nb) acc[mb][nb] = (f32x4){0.f, 0.f, 0.f, 0.f};
#pragma unroll
    for (int r = 0; r < 4; ++r) rs[mb][r] = 0.f;
  }

  // Chunk 0 -> buf 0 (loads issued long ago), then issue chunk 2 (depth 2).
  cvt_store8(&smem[brow * LDB + bcg * 8], ldbuf[0][0], ldbuf[0][1]);
  ldbuf[0][0] = *(const float4*)(LDADDR(2));
  ldbuf[0][1] = *(const float4*)(LDADDR(2) + 4);

  // ---- Steady state: 16 chunks (N-group = c>>2, kc = c&3), 2 chunks in flight.
  // Per iteration: one lgkm-only barrier; prefetch loads cross it untouched.
#pragma unroll
  for (int c = 0; c < NCHUNK; ++c) {
    bar_ds();  // buf[c&1] ready for read; all reads of buf[(c+1)&1] drained
    if (c + 1 < NCHUNK) {  // convert+write chunk c+1 (its loads landed ~2 chunks ago)
      cvt_store8(&smem[((c + 1) & 1) * BUFE + brow * LDB + bcg * 8],
                 ldbuf[(c + 1) & 1][0], ldbuf[(c + 1) & 1][1]);
    }
    if (c + 3 < NCHUNK) {  // issue chunk c+3 into the slot just freed
      ldbuf[(c + 1) & 1][0] = *(const float4*)(LDADDR(c + 3));
      ldbuf[(c + 1) & 1][1] = *(const float4*)(LDADDR(c + 3) + 4);
    }
    const ushort* bs = &smem[(c & 1) * BUFE];
#pragma unroll
    for (int ks = 0; ks < 2; ++ks) {
      bf16x8 bfr[4];
#pragma unroll
      for (int nb = 0; nb < 4; ++nb)
        bfr[nb] = __builtin_bit_cast(
            bf16x8, *(const uint4*)(&bs[(nb * 16 + m15) * LDB + ks * 32 + q * 8]));
#pragma unroll
      for (int mb = 0; mb < 2; ++mb)
#pragma unroll
        for (int nb = 0; nb < 4; ++nb)
          acc[mb][nb] = __builtin_amdgcn_mfma_f32_16x16x32_bf16(
              areg[(c & 3) * 2 + ks][mb], bfr[nb], acc[mb][nb], 0, 0, 0);
    }
    if ((c & 3) == 3) {  // N-group finished (full K): fold exp into row-sums
#pragma unroll
      for (int mb = 0; mb < 2; ++mb)
#pragma unroll
        for (int nb = 0; nb < 4; ++nb)
#pragma unroll
          for (int r = 0; r < 4; ++r)
            rs[mb][r] += __expf(acc[mb][nb][r] * INV_TEMP);
      if (c + 1 < NCHUNK) {
#pragma unroll
        for (int mb = 0; mb < 2; ++mb)
#pragma unroll
          for (int nb = 0; nb < 4; ++nb) acc[mb][nb] = (f32x4){0.f, 0.f, 0.f, 0.f};
      }
    }
  }

  // C/D layout: col = lane&15 (folded), row = wave*32 + mb*16 + q*4 + r.
  // Reduce the 16 lanes of each quad, then one atomic batch per wave.
#pragma unroll
  for (int off = 8; off >= 1; off >>= 1)
#pragma unroll
    for (int mb = 0; mb < 2; ++mb)
#pragma unroll
      for (int r = 0; r < 4; ++r)
        rs[mb][r] += __shfl_xor(rs[mb][r], off, 64);

  if (m15 == 0) {
    float* slot = rowsum + (blockIdx.x & (NSLOT - 1)) * B_;
#pragma unroll
    for (int mb = 0; mb < 2; ++mb)
#pragma unroll
      for (int r = 0; r < 4; ++r)
        atomicAdd(&slot[wave * 32 + mb * 16 + q * 4 + r], rs[mb][r]);
  }
#undef LDADDR

  // ---- Fused finalize: last block to finish computes the loss.
  __syncthreads();  // real sync: drains this block's atomics (vmcnt(0))
  if (tid == 0) {
    __threadfence();  // make this block's rowsum atomics device-visible first
    const unsigned prev = __hip_atomic_fetch_add(counter, 1u, __ATOMIC_ACQ_REL,
                                                 __HIP_MEMORY_SCOPE_AGENT);
    done = (prev == (unsigned)(NBLK - 1)) ? 1u : 0u;
  }
  __syncthreads();
  if (done) {
    __threadfence();  // acquire side: order counter observation before rowsum reads
    float* red = (float*)smem;  // reuse LDS: [0,512) dot partials, [512,768) log terms
    const int b = tid >> 1, part = tid & 1;
    const int t = lab[idx[b]];
    const float4* a4 = (const float4*)(inp + b * D_ + part * 128);
    const float4* c4 = (const float4*)(cf + (size_t)t * D_ + part * 128);
    float dot = 0.f;
#pragma unroll
    for (int i = 0; i < 32; ++i) {
      const float4 x = a4[i], y = c4[i];
      dot += x.x * y.x + x.y * y.y + x.z * y.z + x.w * y.w;
    }
    red[tid] = dot;
    __syncthreads();
    if (tid < 256) {
      const float d = red[2 * tid] + red[2 * tid + 1];
      float S = 0.f;
#pragma unroll
      for (int s = 0; s < NSLOT; ++s)
        S += __hip_atomic_load(&rowsum[s * B_ + tid], __ATOMIC_RELAXED,
                               __HIP_MEMORY_SCOPE_AGENT);
      red[512 + tid] = __logf(__expf(d * INV_TEMP) / (S + EPS_SM) + EPS_LOG);
    }
    __syncthreads();
    for (int off = 128; off >= 1; off >>= 1) {
      if (tid < off) red[512 + tid] += red[512 + tid + off];
      __syncthreads();
    }
    if (tid == 0) out[0] = -red[512] * (1.0f / 256.0f);
  }
}

extern "C" void kernel_launch(void* const* d_in, const int* in_sizes, int n_in,
                              void* d_out, int out_size, void* d_ws, size_t ws_size,
                              hipStream_t stream) {
  const float* inp = (const float*)d_in[0];  // inputs [256,256]
  const float* cf  = (const float*)d_in[1];  // cluster_features [131072,256]
  // d_in[2] = instance_features: unused by the reference
  const int* idx = (const int*)d_in[3];      // indexes [256]
  const int* lab = (const int*)d_in[4];      // labels [131072]
  float* out = (float*)d_out;
  float* rowsum = (float*)d_ws;              // NSLOT * 256 floats
  unsigned* counter = (unsigned*)(rowsum + NSLOT * B_);

  hipMemsetAsync(d_ws, 0, (NSLOT * B_ + 16) * sizeof(float), stream);
  gemm_rowsum_fused<<<dim3(NBLK), dim3(TPB), 0, stream>>>(inp, cf, idx, lab,
                                                          rowsum, counter, out);
}